// Round 12
// baseline (68.984 us; speedup 1.0000x reference)
//
#include <hip/hip_runtime.h>
#include <math.h>

#define B 2048
#define D 64
#define IT 8            // i-rows per main wave
#define NCH 32          // j-chunks for main role
#define CJ (B / NCH)    // 64
#define NC2 16          // j-chunks for the MFMA/LSE role
#define MAIN_BLOCKS 2048
#define LSE_BLOCKS 512

typedef float v2f  __attribute__((ext_vector_type(2)));
typedef short bf16x8 __attribute__((ext_vector_type(8)));
typedef float f32x4  __attribute__((ext_vector_type(4)));

static __device__ __forceinline__ float exp2fast(float x) { return __builtin_amdgcn_exp2f(x); }
static __device__ __forceinline__ float log2fast(float x) { return __builtin_amdgcn_logf(x); }
static __device__ __forceinline__ unsigned short f2bf(float x) {
    unsigned u = __float_as_uint(x);
    u += 0x7fff + ((u >> 16) & 1);          // RNE; inputs are finite
    return (unsigned short)(u >> 16);
}

// ---------------------------------------------------------------------------
// Kernel 1: per-(j,d) constants (log2 units):  lp2 = h*z^2 + g*z + q
// Outputs: pack4 (fp32), Zx/Wt (bf16 MFMA operands), QQ[j]=sum_d q,
// acc zeroed, kl block-partials -> klp[bid] (plain store), out zeroed.
// ---------------------------------------------------------------------------
__global__ __launch_bounds__(256) void k_pre(
    const float* __restrict__ kl, const float* __restrict__ zm,
    const float* __restrict__ zlv, const float* __restrict__ zs,
    float4* __restrict__ pack4, unsigned short* __restrict__ Zx,
    unsigned short* __restrict__ Wt, float* __restrict__ QQ,
    float* __restrict__ acc, float* __restrict__ klp, float* __restrict__ out)
{
    const float LOG2E   = 1.4426950408889634f;
    const float LOG_2PI = 1.8378770664093453f;
    __shared__ float red[4];
    int wv = threadIdx.x >> 6, d = threadIdx.x & 63;
    int j = blockIdx.x * 4 + wv;
    int idx = j * D + d;
    acc[idx] = 0.0f;
    float lv = zlv[idx];
    float mu = zm[idx];
    float zz = zs[idx];
    float is = exp2fast(-LOG2E * lv);            // e^{-lv}
    float h  = -0.5f * LOG2E * is;
    float cv = -0.5f * LOG2E * (lv + LOG_2PI);
    float g  = -2.0f * mu * h;
    float q  = fmaf(mu * mu, h, cv);
    pack4[idx] = make_float4(h, g, q, 0.0f);
    Wt[j * 128 + d]      = f2bf(h);
    Wt[j * 128 + 64 + d] = f2bf(g);
    Zx[j * 128 + d]      = f2bf(zz * zz);
    Zx[j * 128 + 64 + d] = f2bf(zz);

    float qs = q, ks = kl[idx];
#pragma unroll
    for (int off = 32; off; off >>= 1) {
        qs += __shfl_xor(qs, off);
        ks += __shfl_xor(ks, off);
    }
    if (d == 0) { QQ[j] = qs; red[wv] = ks; }
    __syncthreads();
    if (threadIdx.x == 0) {
        klp[blockIdx.x] = red[0] + red[1] + red[2] + red[3];  // kl partial
        if (blockIdx.x == 0) out[0] = 0.0f;                   // zero output
    }
}

// ---------------------------------------------------------------------------
// Role B (lse): s2[i][j] = QQ_j + sum_k Zx[i][k]*Wt[j][k] via 16x16x32 bf16
// MFMA, row-LSE over j fused in epilogue. One wave = 16-i block x 128-j chunk.
// C/D: col = lane&15 (j), row = (lane>>4)*4 + reg (i)  [m89-verified].
// ---------------------------------------------------------------------------
static __device__ __forceinline__ void role_lse(
    int lw, const unsigned short* __restrict__ Zx,
    const unsigned short* __restrict__ Wt, const float* __restrict__ QQ,
    float* __restrict__ wsM, float* __restrict__ wsL)
{
    int lane  = threadIdx.x & 63;
    int i0    = (lw >> 4) * 16;
    int chunk = lw & 15;               // 0..15
    int jbase = chunk * 128;
    int r16 = lane & 15, kg = lane >> 4;

    const bf16x8* Za = (const bf16x8*)(Zx + (size_t)(i0 + r16) * 128 + kg * 8);
    bf16x8 a[4];
#pragma unroll
    for (int s = 0; s < 4; ++s) a[s] = Za[s * 4];   // stride 32 bf16 per K-step

    float m[4], l[4];
#pragma unroll
    for (int r = 0; r < 4; ++r) { m[r] = -3.0e38f; l[r] = 0.0f; }

    for (int t = 0; t < 8; ++t) {
        int j = jbase + t * 16 + r16;
        const bf16x8* Wb = (const bf16x8*)(Wt + (size_t)j * 128 + kg * 8);
        f32x4 c = (f32x4){0.0f, 0.0f, 0.0f, 0.0f};
#pragma unroll
        for (int s = 0; s < 4; ++s)
            c = __builtin_amdgcn_mfma_f32_16x16x32_bf16(a[s], Wb[s * 4], c, 0, 0, 0);
        float qq = QQ[j];
#pragma unroll
        for (int r = 0; r < 4; ++r) {
            float val = c[r] + qq;
            float delta = val - m[r];
            float e = exp2fast(-fabsf(delta));
            l[r] = (delta <= 0.0f) ? (l[r] + e) : fmaf(l[r], e, 1.0f);
            m[r] = fmaxf(m[r], val);
        }
    }
#pragma unroll
    for (int off = 8; off; off >>= 1) {
#pragma unroll
        for (int r = 0; r < 4; ++r) {
            float m2 = __shfl_xor(m[r], off);
            float l2 = __shfl_xor(l[r], off);
            float M  = fmaxf(m[r], m2);
            l[r] = fmaf(l[r], exp2fast(m[r] - M), l2 * exp2fast(m2 - M));
            m[r] = M;
        }
    }
    if (r16 == 0) {
#pragma unroll
        for (int r = 0; r < 4; ++r) {
            int i = i0 + kg * 4 + r;
            wsM[i * NC2 + chunk] = m[r];
            wsL[i * NC2 + chunk] = l[r];
        }
    }
}

// ---------------------------------------------------------------------------
// Kernel 2: blocks [0,512) = lse role AT THE GRID HEAD (short blocks run in
// the first dispatch rounds at full chip occupancy; main streams in behind —
// no exposed tail). Blocks [512,2560) = main role with LDS-staged pack
// window: 4 sub-stages of 16 j (16KB LDS, single buffer), issue-early /
// write-late (T14) so HBM/L2 latency hides under the previous sub-stage's
// exp2 compute; inner loop reads ds_read_b128 (~60cy, off the L1 path).
// chunk = mb&31 keeps one 64KB window per block, same-XCD L2 pinning.
// ---------------------------------------------------------------------------
__global__ __launch_bounds__(256) void k_mega(
    const float* __restrict__ z, const float4* __restrict__ pack4,
    float* __restrict__ acc, const unsigned short* __restrict__ Zx,
    const unsigned short* __restrict__ Wt, const float* __restrict__ QQ,
    float* __restrict__ wsM, float* __restrict__ wsL)
{
    int bid = blockIdx.x;
    int tid = threadIdx.x;
    int wv  = tid >> 6, lane = tid & 63;

    if (bid < LSE_BLOCKS) {
        role_lse(bid * 4 + wv, Zx, Wt, QQ, wsM, wsL);
        return;
    }

    __shared__ float4 sbuf[16 * 64];                 // 16 j x 64 d = 16KB
    int mb = bid - LSE_BLOCKS;                       // 0..2047
    int chunk = mb & (NCH - 1);
    int i0 = ((mb >> 5) * 4 + wv) * IT;
    int j0 = chunk * CJ;

    v2f zrp[IT / 2], zr2p[IT / 2], ap[IT / 2];
#pragma unroll
    for (int kp = 0; kp < IT / 2; ++kp) {
        float za = z[(i0 + 2 * kp) * D + lane];
        float zb = z[(i0 + 2 * kp + 1) * D + lane];
        zrp[kp]  = (v2f){za, zb};
        zr2p[kp] = (v2f){za * za, zb * zb};
        ap[kp]   = (v2f){0.0f, 0.0f};
    }

    // prologue: stage sub-window 0 (1024 float4 = 16KB, 4 per thread)
    float4 streg[4];
#pragma unroll
    for (int r = 0; r < 4; ++r)
        streg[r] = pack4[(size_t)j0 * 64 + r * 256 + tid];
#pragma unroll
    for (int r = 0; r < 4; ++r)
        sbuf[r * 256 + tid] = streg[r];
    __syncthreads();

    for (int s = 0; s < 4; ++s) {
        if (s < 3) {
#pragma unroll
            for (int r = 0; r < 4; ++r)
                streg[r] = pack4[(size_t)(j0 + (s + 1) * 16) * 64 + r * 256 + tid];
        }
        // compute 16 j from LDS
#pragma unroll 4
        for (int jj = 0; jj < 16; ++jj) {
            float4 p = sbuf[jj * 64 + lane];
            v2f hh = (v2f){p.x, p.x};
            v2f gg = (v2f){p.y, p.y};
            v2f qq = (v2f){p.z, p.z};
#pragma unroll
            for (int kp = 0; kp < IT / 2; ++kp) {
                v2f arg = zr2p[kp] * hh + (zrp[kp] * gg + qq);  // 2x v_pk_fma
                v2f e;
                e.x = exp2fast(arg.x);
                e.y = exp2fast(arg.y);
                ap[kp] += e;                                    // v_pk_add
            }
        }
        __syncthreads();
        if (s < 3) {
#pragma unroll
            for (int r = 0; r < 4; ++r)
                sbuf[r * 256 + tid] = streg[r];
        }
        __syncthreads();
    }

#pragma unroll
    for (int kp = 0; kp < IT / 2; ++kp) {
        atomicAdd(&acc[(i0 + 2 * kp) * D + lane], ap[kp].x);
        atomicAdd(&acc[(i0 + 2 * kp + 1) * D + lane], ap[kp].y);
    }
}

// ---------------------------------------------------------------------------
// Kernel 3: per-i finalization, one wave per i; folds the kl partial from
// k_pre (same 512-block grid) into its single atomic per block.
// ---------------------------------------------------------------------------
__global__ __launch_bounds__(256) void k_fin(
    const float* __restrict__ acc, const float* __restrict__ wsM,
    const float* __restrict__ wsL, const float* __restrict__ klp,
    float* __restrict__ out)
{
    const float LN2 = 0.6931471805599453f;
    __shared__ float red[4];
    int lane = threadIdx.x & 63;
    int wv   = threadIdx.x >> 6;
    int i    = blockIdx.x * 4 + wv;

    float lqp2 = log2fast(acc[i * D + lane]);
#pragma unroll
    for (int off = 32; off; off >>= 1) lqp2 += __shfl_xor(lqp2, off);

    float m = -3.0e38f, l = 0.0f;
    if (lane < NC2) { m = wsM[i * NC2 + lane]; l = wsL[i * NC2 + lane]; }
#pragma unroll
    for (int off = 32; off; off >>= 1) {
        float m2 = __shfl_xor(m, off);
        float l2 = __shfl_xor(l, off);
        float M  = fmaxf(m, m2);
        l = fmaf(l, exp2fast(m - M), l2 * exp2fast(m2 - M));
        m = M;
    }

    if (lane == 0)
        red[wv] = (m + log2fast(l) - lqp2) * LN2;
    __syncthreads();
    if (threadIdx.x == 0)
        atomicAdd(out, (red[0] + red[1] + red[2] + red[3]) * (5.0f / 2048.0f)
                       + klp[blockIdx.x]);
}

// ---------------------------------------------------------------------------
extern "C" void kernel_launch(void* const* d_in, const int* in_sizes, int n_in,
                              void* d_out, int out_size, void* d_ws, size_t ws_size,
                              hipStream_t stream)
{
    const float* kl  = (const float*)d_in[0];
    const float* zm  = (const float*)d_in[1];
    const float* zlv = (const float*)d_in[2];
    const float* zs  = (const float*)d_in[3];
    float* out = (float*)d_out;
    float* ws  = (float*)d_ws;

    // workspace layout (floats)
    float4*         pack4 = (float4*)ws;                         // 4*B*D
    unsigned short* Zx    = (unsigned short*)(ws + 4 * B * D);   // B*128 u16
    unsigned short* Wt    = (unsigned short*)(ws + 4 * B * D + (B * 128) / 2);
    float*          QQ    = ws + 4 * B * D + B * 128;            // B
    float*          wsM   = QQ + B;                              // B*NC2
    float*          wsL   = wsM + (size_t)B * NC2;               // B*NC2
    float*          acc   = wsL + (size_t)B * NC2;               // B*D
    float*          klp   = acc + (size_t)B * D;                 // 512

    k_pre<<<B / 4, 256, 0, stream>>>(kl, zm, zlv, zs, pack4, Zx, Wt, QQ, acc, klp, out);
    k_mega<<<LSE_BLOCKS + MAIN_BLOCKS, 256, 0, stream>>>(zs, pack4, acc, Zx, Wt, QQ, wsM, wsL);
    k_fin<<<B / 4, 256, 0, stream>>>(acc, wsM, wsL, klp, out);
}

// Round 13
// 60.192 us; speedup vs baseline: 1.1461x; 1.1461x over previous
//
#include <hip/hip_runtime.h>
#include <math.h>

#define B 2048
#define D 64
#define IT 8            // i-rows per main wave (r5/r11-proven)
#define NCH 32          // j-chunks for main role
#define CJ (B / NCH)    // 64
#define NC2 16          // j-chunks for the MFMA/LSE role
#define MAIN_BLOCKS 2048
#define LSE_BLOCKS 512  // last 512 main blocks also run the lse role

typedef float v2f  __attribute__((ext_vector_type(2)));
typedef short bf16x8 __attribute__((ext_vector_type(8)));
typedef float f32x4  __attribute__((ext_vector_type(4)));

static __device__ __forceinline__ float exp2fast(float x) { return __builtin_amdgcn_exp2f(x); }
static __device__ __forceinline__ float log2fast(float x) { return __builtin_amdgcn_logf(x); }
static __device__ __forceinline__ unsigned short f2bf(float x) {
    unsigned u = __float_as_uint(x);
    u += 0x7fff + ((u >> 16) & 1);          // RNE; inputs are finite
    return (unsigned short)(u >> 16);
}

// ---------------------------------------------------------------------------
// Kernel 1: per-(j,d) constants (log2 units):  lp2 = h*z^2 + g*z + q
// packhg[j*D+d] = { bf16(h)<<16 | bf16(g),  fp32 q }   (8B — main operand)
// Zx/Wt = bf16 MFMA operands; QQ[j]=sum_d q; acc zeroed; kl partials -> klp.
// ---------------------------------------------------------------------------
__global__ __launch_bounds__(256) void k_pre(
    const float* __restrict__ kl, const float* __restrict__ zm,
    const float* __restrict__ zlv, const float* __restrict__ zs,
    uint2* __restrict__ packhg, unsigned short* __restrict__ Zx,
    unsigned short* __restrict__ Wt, float* __restrict__ QQ,
    float* __restrict__ acc, float* __restrict__ klp, float* __restrict__ out)
{
    const float LOG2E   = 1.4426950408889634f;
    const float LOG_2PI = 1.8378770664093453f;
    __shared__ float red[4];
    int wv = threadIdx.x >> 6, d = threadIdx.x & 63;
    int j = blockIdx.x * 4 + wv;
    int idx = j * D + d;
    acc[idx] = 0.0f;
    float lv = zlv[idx];
    float mu = zm[idx];
    float zz = zs[idx];
    float is = exp2fast(-LOG2E * lv);            // e^{-lv}
    float h  = -0.5f * LOG2E * is;
    float cv = -0.5f * LOG2E * (lv + LOG_2PI);
    float g  = -2.0f * mu * h;
    float q  = fmaf(mu * mu, h, cv);
    packhg[idx] = make_uint2(((unsigned)f2bf(h) << 16) | f2bf(g),
                             __float_as_uint(q));
    Wt[j * 128 + d]      = f2bf(h);
    Wt[j * 128 + 64 + d] = f2bf(g);
    Zx[j * 128 + d]      = f2bf(zz * zz);
    Zx[j * 128 + 64 + d] = f2bf(zz);

    float qs = q, ks = kl[idx];
#pragma unroll
    for (int off = 32; off; off >>= 1) {
        qs += __shfl_xor(qs, off);
        ks += __shfl_xor(ks, off);
    }
    if (d == 0) { QQ[j] = qs; red[wv] = ks; }
    __syncthreads();
    if (threadIdx.x == 0) {
        klp[blockIdx.x] = red[0] + red[1] + red[2] + red[3];  // kl partial
        if (blockIdx.x == 0) out[0] = 0.0f;                   // zero output
    }
}

// ---------------------------------------------------------------------------
// Role A (main): acc[i][d] += sum_j 2^(h z^2 + g z + q).
// Wave = IT=8 rows i (4 float2 pairs), one 64-j chunk, lanes own d.
// Params stream 8B/(j,d): bf16 h,g (2-VALU unpack) + fp32 q. The 64-j
// window = 32KB = L1-resident; all 8 blocks on a CU share one window
// (bid mod 256 fixes chunk). unroll 4 keeps 4 loads in flight.
// ---------------------------------------------------------------------------
static __device__ __forceinline__ void role_main(
    int chunk, int igroup, const float* __restrict__ z,
    const uint2* __restrict__ packhg, float* __restrict__ acc)
{
    int lane = threadIdx.x & 63;
    int i0   = igroup * IT;
    int j0   = chunk * CJ;

    v2f zrp[IT / 2], zr2p[IT / 2], ap[IT / 2];
#pragma unroll
    for (int kp = 0; kp < IT / 2; ++kp) {
        float za = z[(i0 + 2 * kp) * D + lane];
        float zb = z[(i0 + 2 * kp + 1) * D + lane];
        zrp[kp]  = (v2f){za, zb};
        zr2p[kp] = (v2f){za * za, zb * zb};
        ap[kp]   = (v2f){0.0f, 0.0f};
    }

#pragma unroll 4
    for (int j = j0; j < j0 + CJ; ++j) {
        uint2 p = packhg[j * D + lane];
        float h = __uint_as_float(p.x & 0xFFFF0000u);
        float g = __uint_as_float(p.x << 16);
        float q = __uint_as_float(p.y);
        v2f hh = (v2f){h, h};
        v2f gg = (v2f){g, g};
        v2f qq = (v2f){q, q};
#pragma unroll
        for (int kp = 0; kp < IT / 2; ++kp) {
            v2f arg = zr2p[kp] * hh + (zrp[kp] * gg + qq);  // 2x v_pk_fma_f32
            v2f e;
            e.x = exp2fast(arg.x);
            e.y = exp2fast(arg.y);
            ap[kp] += e;                                    // v_pk_add_f32
        }
    }
#pragma unroll
    for (int kp = 0; kp < IT / 2; ++kp) {
        atomicAdd(&acc[(i0 + 2 * kp) * D + lane], ap[kp].x);
        atomicAdd(&acc[(i0 + 2 * kp + 1) * D + lane], ap[kp].y);
    }
}

// ---------------------------------------------------------------------------
// Role B (lse): s2[i][j] = QQ_j + sum_k Zx[i][k]*Wt[j][k] via 16x16x32 bf16
// MFMA, row-LSE over j fused in epilogue. One wave = 16-i block x 128-j chunk.
// C/D: col = lane&15 (j), row = (lane>>4)*4 + reg (i)  [m89-verified].
// ---------------------------------------------------------------------------
static __device__ __forceinline__ void role_lse(
    int lw, const unsigned short* __restrict__ Zx,
    const unsigned short* __restrict__ Wt, const float* __restrict__ QQ,
    float* __restrict__ wsM, float* __restrict__ wsL)
{
    int lane  = threadIdx.x & 63;
    int i0    = (lw >> 4) * 16;
    int chunk = lw & 15;               // 0..15
    int jbase = chunk * 128;
    int r16 = lane & 15, kg = lane >> 4;

    const bf16x8* Za = (const bf16x8*)(Zx + (size_t)(i0 + r16) * 128 + kg * 8);
    bf16x8 a[4];
#pragma unroll
    for (int s = 0; s < 4; ++s) a[s] = Za[s * 4];   // stride 32 bf16 per K-step

    float m[4], l[4];
#pragma unroll
    for (int r = 0; r < 4; ++r) { m[r] = -3.0e38f; l[r] = 0.0f; }

    for (int t = 0; t < 8; ++t) {
        int j = jbase + t * 16 + r16;
        const bf16x8* Wb = (const bf16x8*)(Wt + (size_t)j * 128 + kg * 8);
        f32x4 c = (f32x4){0.0f, 0.0f, 0.0f, 0.0f};
#pragma unroll
        for (int s = 0; s < 4; ++s)
            c = __builtin_amdgcn_mfma_f32_16x16x32_bf16(a[s], Wb[s * 4], c, 0, 0, 0);
        float qq = QQ[j];
#pragma unroll
        for (int r = 0; r < 4; ++r) {
            float val = c[r] + qq;
            float delta = val - m[r];
            float e = exp2fast(-fabsf(delta));
            l[r] = (delta <= 0.0f) ? (l[r] + e) : fmaf(l[r], e, 1.0f);
            m[r] = fmaxf(m[r], val);
        }
    }
#pragma unroll
    for (int off = 8; off; off >>= 1) {
#pragma unroll
        for (int r = 0; r < 4; ++r) {
            float m2 = __shfl_xor(m[r], off);
            float l2 = __shfl_xor(l[r], off);
            float M  = fmaxf(m[r], m2);
            l[r] = fmaf(l[r], exp2fast(m[r] - M), l2 * exp2fast(m2 - M));
            m[r] = M;
        }
    }
    if (r16 == 0) {
#pragma unroll
        for (int r = 0; r < 4; ++r) {
            int i = i0 + kg * 4 + r;
            wsM[i * NC2 + chunk] = m[r];
            wsL[i * NC2 + chunk] = l[r];
        }
    }
}

// ---------------------------------------------------------------------------
// Kernel 2: exactly 2048 uniform blocks = 8/CU, ALL resident at t=0 (no
// queue). Every block runs the main role (chunk = bid&31 -> one fixed 32KB
// L1-resident param window per CU). Blocks bid>=1536 additionally run the
// lse role afterwards — exactly 2 such blocks per CU (bids on a CU differ
// by 256), so the lse work is a uniform ~1.3us per-CU tail instead of an
// exposed 2-block/CU phase.
// ---------------------------------------------------------------------------
__global__ __launch_bounds__(256) void k_mega(
    const float* __restrict__ z, const uint2* __restrict__ packhg,
    float* __restrict__ acc, const unsigned short* __restrict__ Zx,
    const unsigned short* __restrict__ Wt, const float* __restrict__ QQ,
    float* __restrict__ wsM, float* __restrict__ wsL)
{
    int wv  = threadIdx.x >> 6;
    int bid = blockIdx.x;
    role_main(bid & (NCH - 1), (bid >> 5) * 4 + wv, z, packhg, acc);
    if (bid >= MAIN_BLOCKS - LSE_BLOCKS) {
        int lw = (bid - (MAIN_BLOCKS - LSE_BLOCKS)) * 4 + wv;   // 0..2047
        role_lse(lw, Zx, Wt, QQ, wsM, wsL);
    }
}

// ---------------------------------------------------------------------------
// Kernel 3: per-i finalization, one wave per i; folds the kl partial from
// k_pre (same 512-block grid) into its single atomic per block.
// ---------------------------------------------------------------------------
__global__ __launch_bounds__(256) void k_fin(
    const float* __restrict__ acc, const float* __restrict__ wsM,
    const float* __restrict__ wsL, const float* __restrict__ klp,
    float* __restrict__ out)
{
    const float LN2 = 0.6931471805599453f;
    __shared__ float red[4];
    int lane = threadIdx.x & 63;
    int wv   = threadIdx.x >> 6;
    int i    = blockIdx.x * 4 + wv;

    float lqp2 = log2fast(acc[i * D + lane]);
#pragma unroll
    for (int off = 32; off; off >>= 1) lqp2 += __shfl_xor(lqp2, off);

    float m = -3.0e38f, l = 0.0f;
    if (lane < NC2) { m = wsM[i * NC2 + lane]; l = wsL[i * NC2 + lane]; }
#pragma unroll
    for (int off = 32; off; off >>= 1) {
        float m2 = __shfl_xor(m, off);
        float l2 = __shfl_xor(l, off);
        float M  = fmaxf(m, m2);
        l = fmaf(l, exp2fast(m - M), l2 * exp2fast(m2 - M));
        m = M;
    }

    if (lane == 0)
        red[wv] = (m + log2fast(l) - lqp2) * LN2;
    __syncthreads();
    if (threadIdx.x == 0)
        atomicAdd(out, (red[0] + red[1] + red[2] + red[3]) * (5.0f / 2048.0f)
                       + klp[blockIdx.x]);
}

// ---------------------------------------------------------------------------
extern "C" void kernel_launch(void* const* d_in, const int* in_sizes, int n_in,
                              void* d_out, int out_size, void* d_ws, size_t ws_size,
                              hipStream_t stream)
{
    const float* kl  = (const float*)d_in[0];
    const float* zm  = (const float*)d_in[1];
    const float* zlv = (const float*)d_in[2];
    const float* zs  = (const float*)d_in[3];
    float* out = (float*)d_out;
    float* ws  = (float*)d_ws;

    // workspace layout (float offsets)
    uint2*          packhg = (uint2*)ws;                         // B*D uint2 = 2BD floats
    unsigned short* Zx     = (unsigned short*)(ws + 2 * B * D);  // B*128 u16 = BD floats
    unsigned short* Wt     = (unsigned short*)(ws + 3 * B * D);  // B*128 u16 = BD floats
    float*          QQ     = ws + 4 * B * D;                     // B
    float*          wsM    = QQ + B;                             // B*NC2
    float*          wsL    = wsM + (size_t)B * NC2;              // B*NC2
    float*          acc    = wsL + (size_t)B * NC2;              // B*D
    float*          klp    = acc + (size_t)B * D;                // 512

    k_pre<<<B / 4, 256, 0, stream>>>(kl, zm, zlv, zs, packhg, Zx, Wt, QQ, acc, klp, out);
    k_mega<<<MAIN_BLOCKS, 256, 0, stream>>>(zs, packhg, acc, Zx, Wt, QQ, wsM, wsL);
    k_fin<<<B / 4, 256, 0, stream>>>(acc, wsM, wsL, klp, out);
}

// Round 14
// 58.187 us; speedup vs baseline: 1.1856x; 1.0345x over previous
//
#include <hip/hip_runtime.h>
#include <math.h>

#define B 2048
#define D 64
#define IT 8            // i-rows per igroup
#define NCH 8           // j-chunks; chunk = bid&7 = XCD id (L2-pinned window)
#define CJ (B / NCH)    // 256 j per chunk, 64 per wave
#define NC2 16          // j-chunks for the MFMA/LSE role
#define NBLK 2048       // main blocks = 256 igroups x 8 chunks

typedef float v2f  __attribute__((ext_vector_type(2)));
typedef short bf16x8 __attribute__((ext_vector_type(8)));
typedef float f32x4  __attribute__((ext_vector_type(4)));

static __device__ __forceinline__ float exp2fast(float x) { return __builtin_amdgcn_exp2f(x); }
static __device__ __forceinline__ float log2fast(float x) { return __builtin_amdgcn_logf(x); }
static __device__ __forceinline__ unsigned short f2bf(float x) {
    unsigned u = __float_as_uint(x);
    u += 0x7fff + ((u >> 16) & 1);          // RNE; inputs are finite
    return (unsigned short)(u >> 16);
}

// ---------------------------------------------------------------------------
// Kernel 1: per-(j,d) constants (log2 units):  lp2 = h*z^2 + g*z + q
// packhg[j*D+d] = { bf16(h)<<16 | bf16(g),  fp32 q }   (8B — main operand)
// Zx/Wt = bf16 MFMA operands; QQ[j]=sum_d q; kl partials -> klp; out zeroed.
// ---------------------------------------------------------------------------
__global__ __launch_bounds__(256) void k_pre(
    const float* __restrict__ kl, const float* __restrict__ zm,
    const float* __restrict__ zlv, const float* __restrict__ zs,
    uint2* __restrict__ packhg, unsigned short* __restrict__ Zx,
    unsigned short* __restrict__ Wt, float* __restrict__ QQ,
    float* __restrict__ klp, float* __restrict__ out)
{
    const float LOG2E   = 1.4426950408889634f;
    const float LOG_2PI = 1.8378770664093453f;
    __shared__ float red[4];
    int wv = threadIdx.x >> 6, d = threadIdx.x & 63;
    int j = blockIdx.x * 4 + wv;
    int idx = j * D + d;
    float lv = zlv[idx];
    float mu = zm[idx];
    float zz = zs[idx];
    float is = exp2fast(-LOG2E * lv);            // e^{-lv}
    float h  = -0.5f * LOG2E * is;
    float cv = -0.5f * LOG2E * (lv + LOG_2PI);
    float g  = -2.0f * mu * h;
    float q  = fmaf(mu * mu, h, cv);
    packhg[idx] = make_uint2(((unsigned)f2bf(h) << 16) | f2bf(g),
                             __float_as_uint(q));
    Wt[j * 128 + d]      = f2bf(h);
    Wt[j * 128 + 64 + d] = f2bf(g);
    Zx[j * 128 + d]      = f2bf(zz * zz);
    Zx[j * 128 + 64 + d] = f2bf(zz);

    float qs = q, ks = kl[idx];
#pragma unroll
    for (int off = 32; off; off >>= 1) {
        qs += __shfl_xor(qs, off);
        ks += __shfl_xor(ks, off);
    }
    if (d == 0) { QQ[j] = qs; red[wv] = ks; }
    __syncthreads();
    if (threadIdx.x == 0) {
        klp[blockIdx.x] = red[0] + red[1] + red[2] + red[3];  // kl partial
        if (blockIdx.x == 0) out[0] = 0.0f;                   // zero output
    }
}

// ---------------------------------------------------------------------------
// Role B (lse): s2[i][j] = QQ_j + sum_k Zx[i][k]*Wt[j][k] via 16x16x32 bf16
// MFMA, row-LSE over j fused in epilogue. One wave = 16-i block x 128-j chunk.
// C/D: col = lane&15 (j), row = (lane>>4)*4 + reg (i)  [m89-verified].
// ---------------------------------------------------------------------------
static __device__ __forceinline__ void role_lse(
    int lw, const unsigned short* __restrict__ Zx,
    const unsigned short* __restrict__ Wt, const float* __restrict__ QQ,
    float* __restrict__ wsM, float* __restrict__ wsL)
{
    int lane  = threadIdx.x & 63;
    int i0    = (lw >> 4) * 16;
    int chunk = lw & 15;               // 0..15
    int jbase = chunk * 128;
    int r16 = lane & 15, kg = lane >> 4;

    const bf16x8* Za = (const bf16x8*)(Zx + (size_t)(i0 + r16) * 128 + kg * 8);
    bf16x8 a[4];
#pragma unroll
    for (int s = 0; s < 4; ++s) a[s] = Za[s * 4];   // stride 32 bf16 per K-step

    float m[4], l[4];
#pragma unroll
    for (int r = 0; r < 4; ++r) { m[r] = -3.0e38f; l[r] = 0.0f; }

    for (int t = 0; t < 8; ++t) {
        int j = jbase + t * 16 + r16;
        const bf16x8* Wb = (const bf16x8*)(Wt + (size_t)j * 128 + kg * 8);
        f32x4 c = (f32x4){0.0f, 0.0f, 0.0f, 0.0f};
#pragma unroll
        for (int s = 0; s < 4; ++s)
            c = __builtin_amdgcn_mfma_f32_16x16x32_bf16(a[s], Wb[s * 4], c, 0, 0, 0);
        float qq = QQ[j];
#pragma unroll
        for (int r = 0; r < 4; ++r) {
            float val = c[r] + qq;
            float delta = val - m[r];
            float e = exp2fast(-fabsf(delta));
            l[r] = (delta <= 0.0f) ? (l[r] + e) : fmaf(l[r], e, 1.0f);
            m[r] = fmaxf(m[r], val);
        }
    }
#pragma unroll
    for (int off = 8; off; off >>= 1) {
#pragma unroll
        for (int r = 0; r < 4; ++r) {
            float m2 = __shfl_xor(m[r], off);
            float l2 = __shfl_xor(l[r], off);
            float M  = fmaxf(m[r], m2);
            l[r] = fmaf(l[r], exp2fast(m[r] - M), l2 * exp2fast(m2 - M));
            m[r] = M;
        }
    }
    if (r16 == 0) {
#pragma unroll
        for (int r = 0; r < 4; ++r) {
            int i = i0 + kg * 4 + r;
            wsM[i * NC2 + chunk] = m[r];
            wsL[i * NC2 + chunk] = l[r];
        }
    }
}

// ---------------------------------------------------------------------------
// Kernel 2: 2048 uniform blocks (8/CU, all resident at t=0).
// Block = (chunk = bid&7, igroup = bid>>3). Wave wv sweeps j-quarter
// [chunk*256 + wv*64, +64) for the block's 8 i's. Partials -> LDS (8KB),
// one barrier, 4-way reduce, ONE plain float2 store per thread into the
// per-chunk slice accS[chunk][i][d] (each element written exactly once —
// ZERO atomics). chunk = bid&7 = XCD id => each chunk's 128KB param window
// is pinned in its own XCD's L2. Wave 0 then runs one lse unit (lw = bid)
// — uniform ~0.7us addition per block, no exposed lse phase.
// ---------------------------------------------------------------------------
__global__ __launch_bounds__(256) void k_mega(
    const float* __restrict__ z, const uint2* __restrict__ packhg,
    float* __restrict__ accS, const unsigned short* __restrict__ Zx,
    const unsigned short* __restrict__ Wt, const float* __restrict__ QQ,
    float* __restrict__ wsM, float* __restrict__ wsL)
{
    __shared__ float lds[4][IT * 64];               // 8KB
    int tid  = threadIdx.x;
    int wv   = tid >> 6, lane = tid & 63;
    int bid  = blockIdx.x;
    int chunk  = bid & (NCH - 1);
    int igroup = bid >> 3;
    int i0 = igroup * IT;
    int j0 = chunk * CJ + wv * 64;

    v2f zrp[IT / 2], zr2p[IT / 2], ap[IT / 2];
#pragma unroll
    for (int kp = 0; kp < IT / 2; ++kp) {
        float za = z[(i0 + 2 * kp) * D + lane];
        float zb = z[(i0 + 2 * kp + 1) * D + lane];
        zrp[kp]  = (v2f){za, zb};
        zr2p[kp] = (v2f){za * za, zb * zb};
        ap[kp]   = (v2f){0.0f, 0.0f};
    }

#pragma unroll 4
    for (int j = j0; j < j0 + 64; ++j) {
        uint2 p = packhg[j * D + lane];
        float h = __uint_as_float(p.x & 0xFFFF0000u);
        float g = __uint_as_float(p.x << 16);
        float q = __uint_as_float(p.y);
        v2f hh = (v2f){h, h};
        v2f gg = (v2f){g, g};
        v2f qq = (v2f){q, q};
#pragma unroll
        for (int kp = 0; kp < IT / 2; ++kp) {
            v2f arg = zr2p[kp] * hh + (zrp[kp] * gg + qq);  // 2x v_pk_fma_f32
            v2f e;
            e.x = exp2fast(arg.x);
            e.y = exp2fast(arg.y);
            ap[kp] += e;                                    // v_pk_add_f32
        }
    }
#pragma unroll
    for (int kp = 0; kp < IT / 2; ++kp) {
        lds[wv][(2 * kp) * 64 + lane]     = ap[kp].x;
        lds[wv][(2 * kp + 1) * 64 + lane] = ap[kp].y;
    }
    __syncthreads();

    // 4-way reduce; thread t owns elements 2t, 2t+1 of the 512-float block
    {
        int e = 2 * tid;
        float s0 = lds[0][e]     + lds[1][e]     + lds[2][e]     + lds[3][e];
        float s1 = lds[0][e + 1] + lds[1][e + 1] + lds[2][e + 1] + lds[3][e + 1];
        float2* dst = (float2*)(accS + (size_t)chunk * B * D + (size_t)i0 * D);
        dst[tid] = make_float2(s0, s1);
    }

    if (wv == 0)
        role_lse(bid, Zx, Wt, QQ, wsM, wsL);   // 2048 units, 1 per block
}

// ---------------------------------------------------------------------------
// Kernel 3: per-i finalization, one wave per i; sums the 8 plain-store
// slices, folds the kl partial (same 512-block grid as k_pre).
// ---------------------------------------------------------------------------
__global__ __launch_bounds__(256) void k_fin(
    const float* __restrict__ accS, const float* __restrict__ wsM,
    const float* __restrict__ wsL, const float* __restrict__ klp,
    float* __restrict__ out)
{
    const float LN2 = 0.6931471805599453f;
    __shared__ float red[4];
    int lane = threadIdx.x & 63;
    int wv   = threadIdx.x >> 6;
    int i    = blockIdx.x * 4 + wv;

    float s = 0.0f;
#pragma unroll
    for (int sl = 0; sl < NCH; ++sl)
        s += accS[(size_t)sl * B * D + i * D + lane];
    float lqp2 = log2fast(s);
#pragma unroll
    for (int off = 32; off; off >>= 1) lqp2 += __shfl_xor(lqp2, off);

    float m = -3.0e38f, l = 0.0f;
    if (lane < NC2) { m = wsM[i * NC2 + lane]; l = wsL[i * NC2 + lane]; }
#pragma unroll
    for (int off = 32; off; off >>= 1) {
        float m2 = __shfl_xor(m, off);
        float l2 = __shfl_xor(l, off);
        float M  = fmaxf(m, m2);
        l = fmaf(l, exp2fast(m - M), l2 * exp2fast(m2 - M));
        m = M;
    }

    if (lane == 0)
        red[wv] = (m + log2fast(l) - lqp2) * LN2;
    __syncthreads();
    if (threadIdx.x == 0)
        atomicAdd(out, (red[0] + red[1] + red[2] + red[3]) * (5.0f / 2048.0f)
                       + klp[blockIdx.x]);
}

// ---------------------------------------------------------------------------
extern "C" void kernel_launch(void* const* d_in, const int* in_sizes, int n_in,
                              void* d_out, int out_size, void* d_ws, size_t ws_size,
                              hipStream_t stream)
{
    const float* kl  = (const float*)d_in[0];
    const float* zm  = (const float*)d_in[1];
    const float* zlv = (const float*)d_in[2];
    const float* zs  = (const float*)d_in[3];
    float* out = (float*)d_out;
    float* ws  = (float*)d_ws;

    // workspace layout (float offsets) — total ~6.6MB
    uint2*          packhg = (uint2*)ws;                         // 2*B*D floats
    unsigned short* Zx     = (unsigned short*)(ws + 2 * B * D);  // B*D floats
    unsigned short* Wt     = (unsigned short*)(ws + 3 * B * D);  // B*D floats
    float*          QQ     = ws + 4 * B * D;                     // B
    float*          wsM    = QQ + B;                             // B*NC2
    float*          wsL    = wsM + (size_t)B * NC2;              // B*NC2
    float*          accS   = wsL + (size_t)B * NC2;              // NCH*B*D
    float*          klp    = accS + (size_t)NCH * B * D;         // 512

    k_pre<<<B / 4, 256, 0, stream>>>(kl, zm, zlv, zs, packhg, Zx, Wt, QQ, klp, out);
    k_mega<<<NBLK, 256, 0, stream>>>(zs, packhg, accS, Zx, Wt, QQ, wsM, wsL);
    k_fin<<<B / 4, 256, 0, stream>>>(accS, wsM, wsL, klp, out);
}

// Round 15
// 57.773 us; speedup vs baseline: 1.1940x; 1.0072x over previous
//
#include <hip/hip_runtime.h>
#include <math.h>

#define B 2048
#define D 64
#define IT 8            // i-rows per igroup
#define NCH 8           // j-chunks; chunk = bid&7 = XCD id (L2-pinned window)
#define CJ (B / NCH)    // 256 j per chunk, 64 per wave
#define NC2 16          // j-chunks for the MFMA/LSE role
#define NBLK 2048       // main blocks = 256 igroups x 8 chunks

typedef float v2f  __attribute__((ext_vector_type(2)));
typedef short bf16x8 __attribute__((ext_vector_type(8)));
typedef float f32x4  __attribute__((ext_vector_type(4)));

static __device__ __forceinline__ float exp2fast(float x) { return __builtin_amdgcn_exp2f(x); }
static __device__ __forceinline__ float log2fast(float x) { return __builtin_amdgcn_logf(x); }
static __device__ __forceinline__ unsigned short f2bf(float x) {
    unsigned u = __float_as_uint(x);
    u += 0x7fff + ((u >> 16) & 1);          // RNE; inputs are finite
    return (unsigned short)(u >> 16);
}

// ---------------------------------------------------------------------------
// Kernel 1: per-(j,d) constants (log2 units):  lp2 = h*z^2 + g*z + q
// For the MAIN role the constants are PRE-SCALED for the Schraudolph
// bit-trick exp2 (no trans pipe):  2^x ~= as_float((int)max(0, h'z^2+g'z+q'))
//   h' = h*2^23 (bf16), g' = g*2^23 (bf16), q' = (q+126.9424)*2^23 (fp32)
//   (126.9424 = 127 - 0.0576 centers the (1+f)/2^f error to mean zero)
// packhg[j*D+d] = { bf16(h')<<16 | bf16(g'),  fp32 q' }   (8B)
// Zx/Wt = bf16 MFMA operands (UNscaled); QQ[j]=sum_d q; kl partials -> klp.
// ---------------------------------------------------------------------------
__global__ __launch_bounds__(256) void k_pre(
    const float* __restrict__ kl, const float* __restrict__ zm,
    const float* __restrict__ zlv, const float* __restrict__ zs,
    uint2* __restrict__ packhg, unsigned short* __restrict__ Zx,
    unsigned short* __restrict__ Wt, float* __restrict__ QQ,
    float* __restrict__ klp, float* __restrict__ out)
{
    const float LOG2E   = 1.4426950408889634f;
    const float LOG_2PI = 1.8378770664093453f;
    const float SC      = 8388608.0f;            // 2^23
    __shared__ float red[4];
    int wv = threadIdx.x >> 6, d = threadIdx.x & 63;
    int j = blockIdx.x * 4 + wv;
    int idx = j * D + d;
    float lv = zlv[idx];
    float mu = zm[idx];
    float zz = zs[idx];
    float is = exp2fast(-LOG2E * lv);            // e^{-lv}
    float h  = -0.5f * LOG2E * is;
    float cv = -0.5f * LOG2E * (lv + LOG_2PI);
    float g  = -2.0f * mu * h;
    float q  = fmaf(mu * mu, h, cv);
    float hs = h * SC;
    float gs = g * SC;
    float qs2 = (q + 126.9424f) * SC;
    packhg[idx] = make_uint2(((unsigned)f2bf(hs) << 16) | f2bf(gs),
                             __float_as_uint(qs2));
    Wt[j * 128 + d]      = f2bf(h);
    Wt[j * 128 + 64 + d] = f2bf(g);
    Zx[j * 128 + d]      = f2bf(zz * zz);
    Zx[j * 128 + 64 + d] = f2bf(zz);

    float qs = q, ks = kl[idx];
#pragma unroll
    for (int off = 32; off; off >>= 1) {
        qs += __shfl_xor(qs, off);
        ks += __shfl_xor(ks, off);
    }
    if (d == 0) { QQ[j] = qs; red[wv] = ks; }
    __syncthreads();
    if (threadIdx.x == 0) {
        klp[blockIdx.x] = red[0] + red[1] + red[2] + red[3];  // kl partial
        if (blockIdx.x == 0) out[0] = 0.0f;                   // zero output
    }
}

// ---------------------------------------------------------------------------
// Role B (lse): s2[i][j] = QQ_j + sum_k Zx[i][k]*Wt[j][k] via 16x16x32 bf16
// MFMA, row-LSE over j fused in epilogue. One wave = 16-i block x 128-j chunk.
// C/D: col = lane&15 (j), row = (lane>>4)*4 + reg (i)  [m89-verified].
// Uses true v_exp_f32 (tiny count — off the hot path).
// ---------------------------------------------------------------------------
static __device__ __forceinline__ void role_lse(
    int lw, const unsigned short* __restrict__ Zx,
    const unsigned short* __restrict__ Wt, const float* __restrict__ QQ,
    float* __restrict__ wsM, float* __restrict__ wsL)
{
    int lane  = threadIdx.x & 63;
    int i0    = (lw >> 4) * 16;
    int chunk = lw & 15;               // 0..15
    int jbase = chunk * 128;
    int r16 = lane & 15, kg = lane >> 4;

    const bf16x8* Za = (const bf16x8*)(Zx + (size_t)(i0 + r16) * 128 + kg * 8);
    bf16x8 a[4];
#pragma unroll
    for (int s = 0; s < 4; ++s) a[s] = Za[s * 4];   // stride 32 bf16 per K-step

    float m[4], l[4];
#pragma unroll
    for (int r = 0; r < 4; ++r) { m[r] = -3.0e38f; l[r] = 0.0f; }

    for (int t = 0; t < 8; ++t) {
        int j = jbase + t * 16 + r16;
        const bf16x8* Wb = (const bf16x8*)(Wt + (size_t)j * 128 + kg * 8);
        f32x4 c = (f32x4){0.0f, 0.0f, 0.0f, 0.0f};
#pragma unroll
        for (int s = 0; s < 4; ++s)
            c = __builtin_amdgcn_mfma_f32_16x16x32_bf16(a[s], Wb[s * 4], c, 0, 0, 0);
        float qq = QQ[j];
#pragma unroll
        for (int r = 0; r < 4; ++r) {
            float val = c[r] + qq;
            float delta = val - m[r];
            float e = exp2fast(-fabsf(delta));
            l[r] = (delta <= 0.0f) ? (l[r] + e) : fmaf(l[r], e, 1.0f);
            m[r] = fmaxf(m[r], val);
        }
    }
#pragma unroll
    for (int off = 8; off; off >>= 1) {
#pragma unroll
        for (int r = 0; r < 4; ++r) {
            float m2 = __shfl_xor(m[r], off);
            float l2 = __shfl_xor(l[r], off);
            float M  = fmaxf(m[r], m2);
            l[r] = fmaf(l[r], exp2fast(m[r] - M), l2 * exp2fast(m2 - M));
            m[r] = M;
        }
    }
    if (r16 == 0) {
#pragma unroll
        for (int r = 0; r < 4; ++r) {
            int i = i0 + kg * 4 + r;
            wsM[i * NC2 + chunk] = m[r];
            wsL[i * NC2 + chunk] = l[r];
        }
    }
}

// ---------------------------------------------------------------------------
// Kernel 2: 2048 uniform blocks (8/CU). Block = (chunk=bid&7, igroup=bid>>3).
// Wave wv sweeps j-quarter [chunk*256 + wv*64, +64) for the block's 8 i's.
// Inner body is ALL full-rate VALU (pk_fma x2, pk_max, cvt_i32 x2, pk_add)
// — zero trans-pipe usage. Partials -> LDS (8KB), one barrier, 4-way
// reduce, plain float2 stores (zero atomics). Wave 0 then runs one lse unit.
// ---------------------------------------------------------------------------
__global__ __launch_bounds__(256) void k_mega(
    const float* __restrict__ z, const uint2* __restrict__ packhg,
    float* __restrict__ accS, const unsigned short* __restrict__ Zx,
    const unsigned short* __restrict__ Wt, const float* __restrict__ QQ,
    float* __restrict__ wsM, float* __restrict__ wsL)
{
    __shared__ float lds[4][IT * 64];               // 8KB
    int tid  = threadIdx.x;
    int wv   = tid >> 6, lane = tid & 63;
    int bid  = blockIdx.x;
    int chunk  = bid & (NCH - 1);
    int igroup = bid >> 3;
    int i0 = igroup * IT;
    int j0 = chunk * CJ + wv * 64;

    v2f zrp[IT / 2], zr2p[IT / 2], ap[IT / 2];
#pragma unroll
    for (int kp = 0; kp < IT / 2; ++kp) {
        float za = z[(i0 + 2 * kp) * D + lane];
        float zb = z[(i0 + 2 * kp + 1) * D + lane];
        zrp[kp]  = (v2f){za, zb};
        zr2p[kp] = (v2f){za * za, zb * zb};
        ap[kp]   = (v2f){0.0f, 0.0f};
    }

#pragma unroll 4
    for (int j = j0; j < j0 + 64; ++j) {
        uint2 p = packhg[j * D + lane];
        float h = __uint_as_float(p.x & 0xFFFF0000u);   // h*2^23 (bf16)
        float g = __uint_as_float(p.x << 16);           // g*2^23 (bf16)
        float q = __uint_as_float(p.y);                 // (q+126.9424)*2^23
        v2f hh = (v2f){h, h};
        v2f gg = (v2f){g, g};
        v2f qq = (v2f){q, q};
#pragma unroll
        for (int kp = 0; kp < IT / 2; ++kp) {
            v2f arg = zr2p[kp] * hh + (zrp[kp] * gg + qq);  // 2x v_pk_fma_f32
            float ax = fmaxf(arg.x, 0.0f);                  // underflow clamp
            float ay = fmaxf(arg.y, 0.0f);
            v2f e = (v2f){__int_as_float((int)ax),          // bits ARE 2^x
                          __int_as_float((int)ay)};
            ap[kp] += e;                                    // v_pk_add_f32
        }
    }
#pragma unroll
    for (int kp = 0; kp < IT / 2; ++kp) {
        lds[wv][(2 * kp) * 64 + lane]     = ap[kp].x;
        lds[wv][(2 * kp + 1) * 64 + lane] = ap[kp].y;
    }
    __syncthreads();

    // 4-way reduce; thread t owns elements 2t, 2t+1 of the 512-float block
    {
        int e = 2 * tid;
        float s0 = lds[0][e]     + lds[1][e]     + lds[2][e]     + lds[3][e];
        float s1 = lds[0][e + 1] + lds[1][e + 1] + lds[2][e + 1] + lds[3][e + 1];
        float2* dst = (float2*)(accS + (size_t)chunk * B * D + (size_t)i0 * D);
        dst[tid] = make_float2(s0, s1);
    }

    if (wv == 0)
        role_lse(bid, Zx, Wt, QQ, wsM, wsL);   // 2048 units, 1 per block
}

// ---------------------------------------------------------------------------
// Kernel 3: per-i finalization, one wave per i; sums the 8 plain-store
// slices, folds the kl partial (same 512-block grid as k_pre).
// ---------------------------------------------------------------------------
__global__ __launch_bounds__(256) void k_fin(
    const float* __restrict__ accS, const float* __restrict__ wsM,
    const float* __restrict__ wsL, const float* __restrict__ klp,
    float* __restrict__ out)
{
    const float LN2 = 0.6931471805599453f;
    __shared__ float red[4];
    int lane = threadIdx.x & 63;
    int wv   = threadIdx.x >> 6;
    int i    = blockIdx.x * 4 + wv;

    float s = 0.0f;
#pragma unroll
    for (int sl = 0; sl < NCH; ++sl)
        s += accS[(size_t)sl * B * D + i * D + lane];
    float lqp2 = log2fast(s);
#pragma unroll
    for (int off = 32; off; off >>= 1) lqp2 += __shfl_xor(lqp2, off);

    float m = -3.0e38f, l = 0.0f;
    if (lane < NC2) { m = wsM[i * NC2 + lane]; l = wsL[i * NC2 + lane]; }
#pragma unroll
    for (int off = 32; off; off >>= 1) {
        float m2 = __shfl_xor(m, off);
        float l2 = __shfl_xor(l, off);
        float M  = fmaxf(m, m2);
        l = fmaf(l, exp2fast(m - M), l2 * exp2fast(m2 - M));
        m = M;
    }

    if (lane == 0)
        red[wv] = (m + log2fast(l) - lqp2) * LN2;
    __syncthreads();
    if (threadIdx.x == 0)
        atomicAdd(out, (red[0] + red[1] + red[2] + red[3]) * (5.0f / 2048.0f)
                       + klp[blockIdx.x]);
}

// ---------------------------------------------------------------------------
extern "C" void kernel_launch(void* const* d_in, const int* in_sizes, int n_in,
                              void* d_out, int out_size, void* d_ws, size_t ws_size,
                              hipStream_t stream)
{
    const float* kl  = (const float*)d_in[0];
    const float* zm  = (const float*)d_in[1];
    const float* zlv = (const float*)d_in[2];
    const float* zs  = (const float*)d_in[3];
    float* out = (float*)d_out;
    float* ws  = (float*)d_ws;

    // workspace layout (float offsets) — total ~6.6MB
    uint2*          packhg = (uint2*)ws;                         // 2*B*D floats
    unsigned short* Zx     = (unsigned short*)(ws + 2 * B * D);  // B*D floats
    unsigned short* Wt     = (unsigned short*)(ws + 3 * B * D);  // B*D floats
    float*          QQ     = ws + 4 * B * D;                     // B
    float*          wsM    = QQ + B;                             // B*NC2
    float*          wsL    = wsM + (size_t)B * NC2;              // B*NC2
    float*          accS   = wsL + (size_t)B * NC2;              // NCH*B*D
    float*          klp    = accS + (size_t)NCH * B * D;         // 512

    k_pre<<<B / 4, 256, 0, stream>>>(kl, zm, zlv, zs, packhg, Zx, Wt, QQ, klp, out);
    k_mega<<<NBLK, 256, 0, stream>>>(zs, packhg, accS, Zx, Wt, QQ, wsM, wsL);
    k_fin<<<B / 4, 256, 0, stream>>>(accS, wsM, wsL, klp, out);
}

// Round 16
// 55.951 us; speedup vs baseline: 1.2329x; 1.0326x over previous
//
#include <hip/hip_runtime.h>
#include <math.h>

#define B 2048
#define D 64
#define IT 8            // i-rows per igroup
#define NCH 8           // j-chunks; chunk = bid&7 = XCD id (L2-pinned window)
#define CJ (B / NCH)    // 256 j per chunk, 64 per wave
#define NC2 16          // j-chunks for the MFMA/LSE role
#define NBLK 2048       // main blocks = 256 igroups x 8 chunks

typedef float v2f  __attribute__((ext_vector_type(2)));
typedef short bf16x8 __attribute__((ext_vector_type(8)));
typedef float f32x4  __attribute__((ext_vector_type(4)));

static __device__ __forceinline__ float exp2fast(float x) { return __builtin_amdgcn_exp2f(x); }
static __device__ __forceinline__ float log2fast(float x) { return __builtin_amdgcn_logf(x); }
static __device__ __forceinline__ unsigned short f2bf(float x) {
    unsigned u = __float_as_uint(x);
    u += 0x7fff + ((u >> 16) & 1);          // RNE; inputs are finite
    return (unsigned short)(u >> 16);
}

// ---------------------------------------------------------------------------
// Kernel 1: per-(j,d) constants, Schraudolph pre-scaled (log2 units x 2^23):
//   h' = h*2^23 (bf16), g' = g*2^23 (bf16), q' = (q+126.9424)*2^23 (fp32)
// NEW 2-j-interleaved layout (one uint4 covers j and j+1 for a given d):
//   u32[ ((j>>1)*D + d)*4 + (j&1)*2 + 0 ] = bf16(h')<<16 | bf16(g')
//   u32[ ((j>>1)*D + d)*4 + (j&1)*2 + 1 ] = bits(q')
// Zx/Wt = bf16 MFMA operands (UNscaled); QQ[j]=sum_d q; kl partials -> klp.
// ---------------------------------------------------------------------------
__global__ __launch_bounds__(256) void k_pre(
    const float* __restrict__ kl, const float* __restrict__ zm,
    const float* __restrict__ zlv, const float* __restrict__ zs,
    unsigned* __restrict__ pk2, unsigned short* __restrict__ Zx,
    unsigned short* __restrict__ Wt, float* __restrict__ QQ,
    float* __restrict__ klp, float* __restrict__ out)
{
    const float LOG2E   = 1.4426950408889634f;
    const float LOG_2PI = 1.8378770664093453f;
    const float SC      = 8388608.0f;            // 2^23
    __shared__ float red[4];
    int wv = threadIdx.x >> 6, d = threadIdx.x & 63;
    int j = blockIdx.x * 4 + wv;
    int idx = j * D + d;
    float lv = zlv[idx];
    float mu = zm[idx];
    float zz = zs[idx];
    float is = exp2fast(-LOG2E * lv);            // e^{-lv}
    float h  = -0.5f * LOG2E * is;
    float cv = -0.5f * LOG2E * (lv + LOG_2PI);
    float g  = -2.0f * mu * h;
    float q  = fmaf(mu * mu, h, cv);
    unsigned hg = ((unsigned)f2bf(h * SC) << 16) | f2bf(g * SC);
    unsigned qb = __float_as_uint((q + 126.9424f) * SC);
    unsigned base = (((unsigned)(j >> 1) * D + d) << 2) + ((j & 1) << 1);
    *(uint2*)(pk2 + base) = make_uint2(hg, qb);  // 8B aligned store

    Wt[j * 128 + d]      = f2bf(h);
    Wt[j * 128 + 64 + d] = f2bf(g);
    Zx[j * 128 + d]      = f2bf(zz * zz);
    Zx[j * 128 + 64 + d] = f2bf(zz);

    float qs = q, ks = kl[idx];
#pragma unroll
    for (int off = 32; off; off >>= 1) {
        qs += __shfl_xor(qs, off);
        ks += __shfl_xor(ks, off);
    }
    if (d == 0) { QQ[j] = qs; red[wv] = ks; }
    __syncthreads();
    if (threadIdx.x == 0) {
        klp[blockIdx.x] = red[0] + red[1] + red[2] + red[3];  // kl partial
        if (blockIdx.x == 0) out[0] = 0.0f;                   // zero output
    }
}

// ---------------------------------------------------------------------------
// Role B (lse): s2[i][j] = QQ_j + sum_k Zx[i][k]*Wt[j][k] via 16x16x32 bf16
// MFMA, row-LSE over j fused in epilogue. One wave = 16-i block x 128-j chunk.
// C/D: col = lane&15 (j), row = (lane>>4)*4 + reg (i)  [m89-verified].
// ---------------------------------------------------------------------------
static __device__ __forceinline__ void role_lse(
    int lw, const unsigned short* __restrict__ Zx,
    const unsigned short* __restrict__ Wt, const float* __restrict__ QQ,
    float* __restrict__ wsM, float* __restrict__ wsL)
{
    int lane  = threadIdx.x & 63;
    int i0    = (lw >> 4) * 16;
    int chunk = lw & 15;               // 0..15
    int jbase = chunk * 128;
    int r16 = lane & 15, kg = lane >> 4;

    const bf16x8* Za = (const bf16x8*)(Zx + (size_t)(i0 + r16) * 128 + kg * 8);
    bf16x8 a[4];
#pragma unroll
    for (int s = 0; s < 4; ++s) a[s] = Za[s * 4];   // stride 32 bf16 per K-step

    float m[4], l[4];
#pragma unroll
    for (int r = 0; r < 4; ++r) { m[r] = -3.0e38f; l[r] = 0.0f; }

    for (int t = 0; t < 8; ++t) {
        int j = jbase + t * 16 + r16;
        const bf16x8* Wb = (const bf16x8*)(Wt + (size_t)j * 128 + kg * 8);
        f32x4 c = (f32x4){0.0f, 0.0f, 0.0f, 0.0f};
#pragma unroll
        for (int s = 0; s < 4; ++s)
            c = __builtin_amdgcn_mfma_f32_16x16x32_bf16(a[s], Wb[s * 4], c, 0, 0, 0);
        float qq = QQ[j];
#pragma unroll
        for (int r = 0; r < 4; ++r) {
            float val = c[r] + qq;
            float delta = val - m[r];
            float e = exp2fast(-fabsf(delta));
            l[r] = (delta <= 0.0f) ? (l[r] + e) : fmaf(l[r], e, 1.0f);
            m[r] = fmaxf(m[r], val);
        }
    }
#pragma unroll
    for (int off = 8; off; off >>= 1) {
#pragma unroll
        for (int r = 0; r < 4; ++r) {
            float m2 = __shfl_xor(m[r], off);
            float l2 = __shfl_xor(l[r], off);
            float M  = fmaxf(m[r], m2);
            l[r] = fmaf(l[r], exp2fast(m[r] - M), l2 * exp2fast(m2 - M));
            m[r] = M;
        }
    }
    if (r16 == 0) {
#pragma unroll
        for (int r = 0; r < 4; ++r) {
            int i = i0 + kg * 4 + r;
            wsM[i * NC2 + chunk] = m[r];
            wsL[i * NC2 + chunk] = l[r];
        }
    }
}

// ---------------------------------------------------------------------------
// Kernel 2: 2048 uniform blocks (8/CU). Block = (chunk=bid&7, igroup=bid>>3).
// Wave wv sweeps j-quarter [chunk*256 + wv*64, +64): 32 uint4 loads (2 j
// each) with an explicit 2-DEEP REGISTER PREFETCH (load pair jp+2 while
// computing jp) so the ~200cy L2 latency hides under ~300cy of compute.
// Inner body per 2 elements: 2 pk_fma (Horner) + 2 max + 2 cvt_u32 + 1
// pk_add — all full-rate VALU, zero trans. Partials -> LDS, 4-way reduce,
// plain float2 stores (zero atomics). Wave 0 then runs one lse unit.
// ---------------------------------------------------------------------------
__global__ __launch_bounds__(256) void k_mega(
    const float* __restrict__ z, const unsigned* __restrict__ pk2,
    float* __restrict__ accS, const unsigned short* __restrict__ Zx,
    const unsigned short* __restrict__ Wt, const float* __restrict__ QQ,
    float* __restrict__ wsM, float* __restrict__ wsL)
{
    __shared__ float lds[4][IT * 64];               // 8KB
    int tid  = threadIdx.x;
    int wv   = tid >> 6, lane = tid & 63;
    int bid  = blockIdx.x;
    int chunk  = bid & (NCH - 1);
    int igroup = bid >> 3;
    int i0 = igroup * IT;
    int j0 = chunk * CJ + wv * 64;

    v2f zrp[IT / 2], ap[IT / 2];
#pragma unroll
    for (int kp = 0; kp < IT / 2; ++kp) {
        float za = z[(i0 + 2 * kp) * D + lane];
        float zb = z[(i0 + 2 * kp + 1) * D + lane];
        zrp[kp] = (v2f){za, zb};
        ap[kp]  = (v2f){0.0f, 0.0f};
    }

    // uint4 stream: index (j0/2 + jp)*D + lane, jp = 0..31
    const uint4* Pw = (const uint4*)pk2 + ((size_t)(j0 >> 1)) * D + lane;
    uint4 bufA = Pw[0];
    uint4 bufB = Pw[D];

#pragma unroll 4
    for (int jp = 0; jp < 32; ++jp) {
        uint4 cur = bufA;
        bufA = bufB;
        bufB = Pw[(size_t)(jp + 2) * D];   // benign OOB (lands in Zx) for jp>=30
        // two j's: (cur.x=hg_e, cur.y=q_e) even, (cur.z=hg_o, cur.w=q_o) odd
        float he = __uint_as_float(cur.x & 0xFFFF0000u);
        float ge = __uint_as_float(cur.x << 16);
        float qe = __uint_as_float(cur.y);
        float ho = __uint_as_float(cur.z & 0xFFFF0000u);
        float go = __uint_as_float(cur.z << 16);
        float qo = __uint_as_float(cur.w);
        v2f hev = (v2f){he, he}, gev = (v2f){ge, ge}, qev = (v2f){qe, qe};
        v2f hov = (v2f){ho, ho}, gov = (v2f){go, go}, qov = (v2f){qo, qo};
#pragma unroll
        for (int kp = 0; kp < IT / 2; ++kp) {
            v2f t  = zrp[kp] * hev + gev;            // Horner: (h z + g)
            v2f a1 = zrp[kp] * t + qev;              //   z(hz+g) + q'
            ap[kp] += (v2f){__uint_as_float((unsigned)fmaxf(a1.x, 0.0f)),
                            __uint_as_float((unsigned)fmaxf(a1.y, 0.0f))};
            v2f t2 = zrp[kp] * hov + gov;
            v2f a2 = zrp[kp] * t2 + qov;
            ap[kp] += (v2f){__uint_as_float((unsigned)fmaxf(a2.x, 0.0f)),
                            __uint_as_float((unsigned)fmaxf(a2.y, 0.0f))};
        }
    }

#pragma unroll
    for (int kp = 0; kp < IT / 2; ++kp) {
        lds[wv][(2 * kp) * 64 + lane]     = ap[kp].x;
        lds[wv][(2 * kp + 1) * 64 + lane] = ap[kp].y;
    }
    __syncthreads();

    // 4-way reduce; thread t owns elements 2t, 2t+1 of the 512-float block
    {
        int e = 2 * tid;
        float s0 = lds[0][e]     + lds[1][e]     + lds[2][e]     + lds[3][e];
        float s1 = lds[0][e + 1] + lds[1][e + 1] + lds[2][e + 1] + lds[3][e + 1];
        float2* dst = (float2*)(accS + (size_t)chunk * B * D + (size_t)i0 * D);
        dst[tid] = make_float2(s0, s1);
    }

    if (wv == 0)
        role_lse(bid, Zx, Wt, QQ, wsM, wsL);   // 2048 units, 1 per block
}

// ---------------------------------------------------------------------------
// Kernel 3: per-i finalization, one wave per i; sums the 8 plain-store
// slices, folds the kl partial (same 512-block grid as k_pre).
// ---------------------------------------------------------------------------
__global__ __launch_bounds__(256) void k_fin(
    const float* __restrict__ accS, const float* __restrict__ wsM,
    const float* __restrict__ wsL, const float* __restrict__ klp,
    float* __restrict__ out)
{
    const float LN2 = 0.6931471805599453f;
    __shared__ float red[4];
    int lane = threadIdx.x & 63;
    int wv   = threadIdx.x >> 6;
    int i    = blockIdx.x * 4 + wv;

    float s = 0.0f;
#pragma unroll
    for (int sl = 0; sl < NCH; ++sl)
        s += accS[(size_t)sl * B * D + i * D + lane];
    float lqp2 = log2fast(s);
#pragma unroll
    for (int off = 32; off; off >>= 1) lqp2 += __shfl_xor(lqp2, off);

    float m = -3.0e38f, l = 0.0f;
    if (lane < NC2) { m = wsM[i * NC2 + lane]; l = wsL[i * NC2 + lane]; }
#pragma unroll
    for (int off = 32; off; off >>= 1) {
        float m2 = __shfl_xor(m, off);
        float l2 = __shfl_xor(l, off);
        float M  = fmaxf(m, m2);
        l = fmaf(l, exp2fast(m - M), l2 * exp2fast(m2 - M));
        m = M;
    }

    if (lane == 0)
        red[wv] = (m + log2fast(l) - lqp2) * LN2;
    __syncthreads();
    if (threadIdx.x == 0)
        atomicAdd(out, (red[0] + red[1] + red[2] + red[3]) * (5.0f / 2048.0f)
                       + klp[blockIdx.x]);
}

// ---------------------------------------------------------------------------
extern "C" void kernel_launch(void* const* d_in, const int* in_sizes, int n_in,
                              void* d_out, int out_size, void* d_ws, size_t ws_size,
                              hipStream_t stream)
{
    const float* kl  = (const float*)d_in[0];
    const float* zm  = (const float*)d_in[1];
    const float* zlv = (const float*)d_in[2];
    const float* zs  = (const float*)d_in[3];
    float* out = (float*)d_out;
    float* ws  = (float*)d_ws;

    // workspace layout (float offsets) — total ~6.6MB
    unsigned*       pk2  = (unsigned*)ws;                        // 2*B*D floats
    unsigned short* Zx   = (unsigned short*)(ws + 2 * B * D);    // B*D floats
    unsigned short* Wt   = (unsigned short*)(ws + 3 * B * D);    // B*D floats
    float*          QQ   = ws + 4 * B * D;                       // B
    float*          wsM  = QQ + B;                               // B*NC2
    float*          wsL  = wsM + (size_t)B * NC2;                // B*NC2
    float*          accS = wsL + (size_t)B * NC2;                // NCH*B*D
    float*          klp  = accS + (size_t)NCH * B * D;           // 512

    k_pre<<<B / 4, 256, 0, stream>>>(kl, zm, zlv, zs, pk2, Zx, Wt, QQ, klp, out);
    k_mega<<<NBLK, 256, 0, stream>>>(zs, pk2, accS, Zx, Wt, QQ, wsM, wsL);
    k_fin<<<B / 4, 256, 0, stream>>>(accS, wsM, wsL, klp, out);
}

// Round 17
// 42.894 us; speedup vs baseline: 1.6082x; 1.3044x over previous
//
#include <hip/hip_runtime.h>
#include <math.h>

#define B 2048
#define D 64
#define G 512           // z-grid points for the F_d(z) table
#define NCH 32          // j-chunks; block = (tgroup, chunk)
#define NC2 16          // j-chunks for the MFMA/LSE role
#define NBLK 2048       // (G/8) tgroups x 32 chunks

#define ZLO (-5.5f)
#define DZ  (11.0f / 511.0f)
#define INVDZ (511.0f / 11.0f)

typedef float v2f  __attribute__((ext_vector_type(2)));
typedef short bf16x8 __attribute__((ext_vector_type(8)));
typedef float f32x4  __attribute__((ext_vector_type(4)));

static __device__ __forceinline__ float exp2fast(float x) { return __builtin_amdgcn_exp2f(x); }
static __device__ __forceinline__ float log2fast(float x) { return __builtin_amdgcn_logf(x); }
static __device__ __forceinline__ unsigned short f2bf(float x) {
    unsigned u = __float_as_uint(x);
    u += 0x7fff + ((u >> 16) & 1);          // RNE; inputs are finite
    return (unsigned short)(u >> 16);
}

// ---------------------------------------------------------------------------
// Kernel 1: per-(j,d) constants (log2 units):  lp2 = h*z^2 + g*z + q
//   h = -0.5*log2e*exp(-lv), g = -2*mu*h, q = mu^2*h + c
// packhg[j*D+d] = { bf16(h)<<16 | bf16(g), fp32 q }  (8B, UNscaled)
// Zx/Wt = bf16 MFMA operands; QQ[j]=sum_d q; kl partials -> klp; out zeroed.
// ---------------------------------------------------------------------------
__global__ __launch_bounds__(256) void k_pre(
    const float* __restrict__ kl, const float* __restrict__ zm,
    const float* __restrict__ zlv, const float* __restrict__ zs,
    uint2* __restrict__ packhg, unsigned short* __restrict__ Zx,
    unsigned short* __restrict__ Wt, float* __restrict__ QQ,
    float* __restrict__ klp, float* __restrict__ out)
{
    const float LOG2E   = 1.4426950408889634f;
    const float LOG_2PI = 1.8378770664093453f;
    __shared__ float red[4];
    int wv = threadIdx.x >> 6, d = threadIdx.x & 63;
    int j = blockIdx.x * 4 + wv;
    int idx = j * D + d;
    float lv = zlv[idx];
    float mu = zm[idx];
    float zz = zs[idx];
    float is = exp2fast(-LOG2E * lv);            // e^{-lv}
    float h  = -0.5f * LOG2E * is;
    float cv = -0.5f * LOG2E * (lv + LOG_2PI);
    float g  = -2.0f * mu * h;
    float q  = fmaf(mu * mu, h, cv);
    packhg[idx] = make_uint2(((unsigned)f2bf(h) << 16) | f2bf(g),
                             __float_as_uint(q));
    Wt[j * 128 + d]      = f2bf(h);
    Wt[j * 128 + 64 + d] = f2bf(g);
    Zx[j * 128 + d]      = f2bf(zz * zz);
    Zx[j * 128 + 64 + d] = f2bf(zz);

    float qs = q, ks = kl[idx];
#pragma unroll
    for (int off = 32; off; off >>= 1) {
        qs += __shfl_xor(qs, off);
        ks += __shfl_xor(ks, off);
    }
    if (d == 0) { QQ[j] = qs; red[wv] = ks; }
    __syncthreads();
    if (threadIdx.x == 0) {
        klp[blockIdx.x] = red[0] + red[1] + red[2] + red[3];  // kl partial
        if (blockIdx.x == 0) out[0] = 0.0f;                   // zero output
    }
}

// ---------------------------------------------------------------------------
// Role B (lse): s2[i][j] = QQ_j + sum_k Zx[i][k]*Wt[j][k] via 16x16x32 bf16
// MFMA, row-LSE over j fused in epilogue. One wave = 16-i block x 128-j chunk.
// C/D: col = lane&15 (j), row = (lane>>4)*4 + reg (i)  [m89-verified].
// ---------------------------------------------------------------------------
static __device__ __forceinline__ void role_lse(
    int lw, const unsigned short* __restrict__ Zx,
    const unsigned short* __restrict__ Wt, const float* __restrict__ QQ,
    float* __restrict__ wsM, float* __restrict__ wsL)
{
    int lane  = threadIdx.x & 63;
    int i0    = (lw >> 4) * 16;
    int chunk = lw & 15;               // 0..15
    int jbase = chunk * 128;
    int r16 = lane & 15, kg = lane >> 4;

    const bf16x8* Za = (const bf16x8*)(Zx + (size_t)(i0 + r16) * 128 + kg * 8);
    bf16x8 a[4];
#pragma unroll
    for (int s = 0; s < 4; ++s) a[s] = Za[s * 4];   // stride 32 bf16 per K-step

    float m[4], l[4];
#pragma unroll
    for (int r = 0; r < 4; ++r) { m[r] = -3.0e38f; l[r] = 0.0f; }

    for (int t = 0; t < 8; ++t) {
        int j = jbase + t * 16 + r16;
        const bf16x8* Wb = (const bf16x8*)(Wt + (size_t)j * 128 + kg * 8);
        f32x4 c = (f32x4){0.0f, 0.0f, 0.0f, 0.0f};
#pragma unroll
        for (int s = 0; s < 4; ++s)
            c = __builtin_amdgcn_mfma_f32_16x16x32_bf16(a[s], Wb[s * 4], c, 0, 0, 0);
        float qq = QQ[j];
#pragma unroll
        for (int r = 0; r < 4; ++r) {
            float val = c[r] + qq;
            float delta = val - m[r];
            float e = exp2fast(-fabsf(delta));
            l[r] = (delta <= 0.0f) ? (l[r] + e) : fmaf(l[r], e, 1.0f);
            m[r] = fmaxf(m[r], val);
        }
    }
#pragma unroll
    for (int off = 8; off; off >>= 1) {
#pragma unroll
        for (int r = 0; r < 4; ++r) {
            float m2 = __shfl_xor(m[r], off);
            float l2 = __shfl_xor(l[r], off);
            float M  = fmaxf(m[r], m2);
            l[r] = fmaf(l[r], exp2fast(m[r] - M), l2 * exp2fast(m2 - M));
            m[r] = M;
        }
    }
    if (r16 == 0) {
#pragma unroll
        for (int r = 0; r < 4; ++r) {
            int i = i0 + kg * 4 + r;
            wsM[i * NC2 + chunk] = m[r];
            wsL[i * NC2 + chunk] = l[r];
        }
    }
}

// ---------------------------------------------------------------------------
// Kernel 2: TABLE BUILD. F_d(z_t) = sum_j 2^(h z_t^2 + g z_t + q) evaluated
// on the G=512 z-grid instead of the 2048 z samples — 4x less work; the
// (i,d) values are recovered by interpolation in k_fin.
// 2048 uniform blocks: tgroup = bid>>5 (8 t's), chunk = bid&31 (64-j window);
// wave wv sweeps 16 j for all 8 t's (4 v2f t-pairs; z_t is lane-uniform).
// Partials -> LDS (8KB), 4-way reduce, plain float2 stores into
// accS[chunk][t][d] (zero atomics). Wave 0 then runs one lse unit.
// ---------------------------------------------------------------------------
__global__ __launch_bounds__(256) void k_mega(
    const uint2* __restrict__ packhg, float* __restrict__ accS,
    const unsigned short* __restrict__ Zx, const unsigned short* __restrict__ Wt,
    const float* __restrict__ QQ, float* __restrict__ wsM, float* __restrict__ wsL)
{
    __shared__ float lds[4][8 * 64];                // 8KB
    int tid  = threadIdx.x;
    int wv   = tid >> 6, lane = tid & 63;
    int bid  = blockIdx.x;
    int chunk = bid & (NCH - 1);
    int t0    = (bid >> 5) * 8;
    int j0    = chunk * 64 + wv * 16;

    v2f zt[4], zt2[4], ap[4];
#pragma unroll
    for (int kp = 0; kp < 4; ++kp) {
        float za = ZLO + (float)(t0 + 2 * kp) * DZ;
        float zb = ZLO + (float)(t0 + 2 * kp + 1) * DZ;
        zt[kp]  = (v2f){za, zb};
        zt2[kp] = (v2f){za * za, zb * zb};
        ap[kp]  = (v2f){0.0f, 0.0f};
    }

#pragma unroll 4
    for (int j = j0; j < j0 + 16; ++j) {
        uint2 p = packhg[j * D + lane];
        float h = __uint_as_float(p.x & 0xFFFF0000u);
        float g = __uint_as_float(p.x << 16);
        float q = __uint_as_float(p.y);
        v2f hh = (v2f){h, h};
        v2f gg = (v2f){g, g};
        v2f qq = (v2f){q, q};
#pragma unroll
        for (int kp = 0; kp < 4; ++kp) {
            v2f arg = zt2[kp] * hh + (zt[kp] * gg + qq);  // 2x v_pk_fma_f32
            v2f e;
            e.x = exp2fast(arg.x);
            e.y = exp2fast(arg.y);
            ap[kp] += e;                                  // v_pk_add_f32
        }
    }

#pragma unroll
    for (int kp = 0; kp < 4; ++kp) {
        lds[wv][(2 * kp) * 64 + lane]     = ap[kp].x;
        lds[wv][(2 * kp + 1) * 64 + lane] = ap[kp].y;
    }
    __syncthreads();
    {
        int e = 2 * tid;
        float s0 = lds[0][e]     + lds[1][e]     + lds[2][e]     + lds[3][e];
        float s1 = lds[0][e + 1] + lds[1][e + 1] + lds[2][e + 1] + lds[3][e + 1];
        float2* dst = (float2*)(accS + (size_t)chunk * G * D + (size_t)t0 * D);
        dst[tid] = make_float2(s0, s1);
    }

    if (wv == 0)
        role_lse(bid, Zx, Wt, QQ, wsM, wsL);   // 2048 units, 1 per block
}

// ---------------------------------------------------------------------------
// Kernel 2b: reduce the 32 chunk slices and take log2 -> T[t*64+d].
// ---------------------------------------------------------------------------
__global__ __launch_bounds__(256) void k_tab(
    const float* __restrict__ accS, float* __restrict__ T)
{
    int e = blockIdx.x * 256 + threadIdx.x;    // 0 .. G*D-1
    float s = 0.0f;
#pragma unroll
    for (int c = 0; c < NCH; ++c)
        s += accS[(size_t)c * G * D + e];
    T[e] = log2fast(s);
}

// ---------------------------------------------------------------------------
// Kernel 3: per-i finalization, one wave per i. lane owns d: Catmull-Rom
// interpolation of T at z[i][d] -> log2 F_d(z_id); butterfly-sum -> lqp2.
// Then the wsM/wsL chunk merge (log_qz), kl fold, one atomic per block.
// ---------------------------------------------------------------------------
__global__ __launch_bounds__(256) void k_fin(
    const float* __restrict__ z, const float* __restrict__ T,
    const float* __restrict__ wsM, const float* __restrict__ wsL,
    const float* __restrict__ klp, float* __restrict__ out)
{
    const float LN2 = 0.6931471805599453f;
    __shared__ float red[4];
    int lane = threadIdx.x & 63;
    int wv   = threadIdx.x >> 6;
    int i    = blockIdx.x * 4 + wv;

    float zv = z[i * D + lane];
    float tf = (zv - ZLO) * INVDZ;
    int   it = (int)floorf(tf);
    it = min(max(it, 1), G - 3);
    float u = tf - (float)it;
    float y0 = T[(it - 1) * D + lane];
    float y1 = T[it * D + lane];
    float y2 = T[(it + 1) * D + lane];
    float y3 = T[(it + 2) * D + lane];
    float ca = fmaf(1.5f, y1 - y2, 0.5f * (y3 - y0));
    float cb = y0 - 2.5f * y1 + 2.0f * y2 - 0.5f * y3;
    float cc = 0.5f * (y2 - y0);
    float lqp2 = fmaf(fmaf(fmaf(ca, u, cb), u, cc), u, y1);
#pragma unroll
    for (int off = 32; off; off >>= 1) lqp2 += __shfl_xor(lqp2, off);

    float m = -3.0e38f, l = 0.0f;
    if (lane < NC2) { m = wsM[i * NC2 + lane]; l = wsL[i * NC2 + lane]; }
#pragma unroll
    for (int off = 32; off; off >>= 1) {
        float m2 = __shfl_xor(m, off);
        float l2 = __shfl_xor(l, off);
        float M  = fmaxf(m, m2);
        l = fmaf(l, exp2fast(m - M), l2 * exp2fast(m2 - M));
        m = M;
    }

    if (lane == 0)
        red[wv] = (m + log2fast(l) - lqp2) * LN2;
    __syncthreads();
    if (threadIdx.x == 0)
        atomicAdd(out, (red[0] + red[1] + red[2] + red[3]) * (5.0f / 2048.0f)
                       + klp[blockIdx.x]);
}

// ---------------------------------------------------------------------------
extern "C" void kernel_launch(void* const* d_in, const int* in_sizes, int n_in,
                              void* d_out, int out_size, void* d_ws, size_t ws_size,
                              hipStream_t stream)
{
    const float* kl  = (const float*)d_in[0];
    const float* zm  = (const float*)d_in[1];
    const float* zlv = (const float*)d_in[2];
    const float* zs  = (const float*)d_in[3];
    float* out = (float*)d_out;
    float* ws  = (float*)d_ws;

    // workspace layout (float offsets) — total ~6.7MB
    uint2*          packhg = (uint2*)ws;                         // 2*B*D floats
    unsigned short* Zx   = (unsigned short*)(ws + 2 * B * D);    // B*D floats
    unsigned short* Wt   = (unsigned short*)(ws + 3 * B * D);    // B*D floats
    float*          QQ   = ws + 4 * B * D;                       // B
    float*          wsM  = QQ + B;                               // B*NC2
    float*          wsL  = wsM + (size_t)B * NC2;                // B*NC2
    float*          accS = wsL + (size_t)B * NC2;                // NCH*G*D
    float*          T    = accS + (size_t)NCH * G * D;           // G*D
    float*          klp  = T + (size_t)G * D;                    // 512

    k_pre<<<B / 4, 256, 0, stream>>>(kl, zm, zlv, zs, packhg, Zx, Wt, QQ, klp, out);
    k_mega<<<NBLK, 256, 0, stream>>>(packhg, accS, Zx, Wt, QQ, wsM, wsL);
    k_tab<<<(G * D) / 256, 256, 0, stream>>>(accS, T);
    k_fin<<<B / 4, 256, 0, stream>>>(zs, T, wsM, wsL, klp, out);
}